// Round 11
// baseline (434.552 us; speedup 1.0000x reference)
//
#include <hip/hip_runtime.h>

#define NF 256   // input features
#define NK 256   // filters / output features
#define NBKT 512          // coarse buckets (256 nodes each)
#define TILEA 8192        // edges per bin_coarse block

typedef __attribute__((ext_vector_type(8))) short bf16x8;
typedef __attribute__((ext_vector_type(4))) float f32x4;
typedef __attribute__((ext_vector_type(2))) float f32x2;

__device__ __forceinline__ ushort f2bf(float f) {
  uint u = __float_as_uint(f);
  return (ushort)((u + 0x7fffu + ((u >> 16) & 1u)) >> 16);  // RNE
}
__device__ __forceinline__ float bf2f(ushort h) {
  return __uint_as_float(((uint)h) << 16);
}

// ---------------------------------------------------------------------------
// Prelude (fused): blocks [0,256) transpose filters f32->bf16 Ft[N][K];
// blocks [256, 256+2048) do the coarse bucket histogram (row>>8).
// ---------------------------------------------------------------------------
__global__ __launch_bounds__(256) void prelude(const float* __restrict__ F,
                                               ushort* __restrict__ Ft,
                                               const int* __restrict__ erow,
                                               int* __restrict__ bcnt, int nE) {
  __shared__ int h[NBKT];
  if (blockIdx.x < NF) {
    int k = blockIdx.x;
    int n = threadIdx.x;
    Ft[(size_t)n * NF + k] = f2bf(F[(size_t)k * NK + n]);
    return;
  }
  const int bid = blockIdx.x - NF;
  const int nb = gridDim.x - NF;
  h[threadIdx.x] = 0;
  h[threadIdx.x + 256] = 0;
  __syncthreads();
  for (int e = bid * 256 + threadIdx.x; e < nE; e += nb * 256)
    atomicAdd(&h[erow[e] >> 8], 1);
  __syncthreads();
  int v0 = h[threadIdx.x], v1 = h[threadIdx.x + 256];
  if (v0) atomicAdd(&bcnt[threadIdx.x], v0);
  if (v1) atomicAdd(&bcnt[threadIdx.x + 256], v1);
}

// ---------------------------------------------------------------------------
// MFMA GEMM: 32 rows/block, B-frag reuse x2 (verified round 8).
// ---------------------------------------------------------------------------
__global__ __launch_bounds__(256) void gemm_mfma(const float* __restrict__ x,
                                                 const ushort* __restrict__ Ft,
                                                 ushort* __restrict__ XFh, int M) {
  __shared__ ushort As[32 * NF];  // 16 KB, swizzled
  const int t = threadIdx.x;
  const int row0 = blockIdx.x * 32;

  const float4* xv = (const float4*)(x + (size_t)row0 * NF);
#pragma unroll
  for (int j = 0; j < 8; ++j) {
    int idx = j * 256 + t;
    int r = idx >> 6;
    int c4 = idx & 63;
    float4 v = make_float4(0.f, 0.f, 0.f, 0.f);
    if (row0 + r < M) v = xv[idx];
    ushort4 hh = make_ushort4(f2bf(v.x), f2bf(v.y), f2bf(v.z), f2bf(v.w));
    uint boff = (uint)(r * 512 + c4 * 8);
    boff ^= (uint)((r & 7) << 4);
    *(ushort4*)((char*)As + boff) = hh;
  }
  __syncthreads();

  const int lane = t & 63;
  const int wv = t >> 6;
  const int arow = lane & 15;
  const int kg = lane >> 4;

  bf16x8 afr[2][8];
#pragma unroll
  for (int rt = 0; rt < 2; ++rt) {
#pragma unroll
    for (int kk = 0; kk < 8; ++kk) {
      int r = rt * 16 + arow;
      uint boff = (uint)(r * 512 + kk * 64 + kg * 16);
      boff ^= (uint)((r & 7) << 4);
      afr[rt][kk] = *(const bf16x8*)((const char*)As + boff);
    }
  }

  f32x4 acc[2][4];
#pragma unroll
  for (int rt = 0; rt < 2; ++rt)
#pragma unroll
    for (int f = 0; f < 4; ++f) acc[rt][f] = (f32x4){0.f, 0.f, 0.f, 0.f};

  const int ncol0 = wv * 64;
#pragma unroll
  for (int f = 0; f < 4; ++f) {
    const ushort* bp = Ft + (size_t)(ncol0 + f * 16 + arow) * NF + kg * 8;
#pragma unroll
    for (int kk = 0; kk < 8; ++kk) {
      bf16x8 bfr = *(const bf16x8*)(bp + kk * 32);
      acc[0][f] = __builtin_amdgcn_mfma_f32_16x16x32_bf16(afr[0][kk], bfr, acc[0][f], 0, 0, 0);
      acc[1][f] = __builtin_amdgcn_mfma_f32_16x16x32_bf16(afr[1][kk], bfr, acc[1][f], 0, 0, 0);
    }
  }

#pragma unroll
  for (int rt = 0; rt < 2; ++rt) {
#pragma unroll
    for (int f = 0; f < 4; ++f) {
      int col = ncol0 + f * 16 + arow;
#pragma unroll
      for (int rg = 0; rg < 4; ++rg) {
        int row = row0 + rt * 16 + kg * 4 + rg;
        if (row < M) XFh[(size_t)row * NK + col] = f2bf(acc[rt][f][rg]);
      }
    }
  }
}

// 1 block, 512 threads: exclusive scan of bcnt -> bbase + bcursor (padded)
__global__ __launch_bounds__(512) void scan_bbase(const int* __restrict__ bcnt,
                                                  int* __restrict__ bbase,
                                                  int* __restrict__ bcursor) {
  __shared__ int s[NBKT];
  int t = threadIdx.x;
  int v = bcnt[t];
  s[t] = v;
  __syncthreads();
  for (int d = 1; d < NBKT; d <<= 1) {
    int tmp = (t >= d) ? s[t - d] : 0;
    __syncthreads();
    s[t] += tmp;
    __syncthreads();
  }
  int excl = s[t] - v;
  bbase[t] = excl;
  bcursor[t * 16] = excl;
}

// ---------------------------------------------------------------------------
// Pass A: coarse bin with LDS permute -> wave-contiguous global runs.
// Payload packs (col | local<<20, w).
// ---------------------------------------------------------------------------
__global__ __launch_bounds__(512) void bin_coarse(const int* __restrict__ erow,
                                                  const int* __restrict__ ecol,
                                                  const float* __restrict__ ew,
                                                  int* __restrict__ bcursor,
                                                  int2* __restrict__ tmpCW, int nE) {
  __shared__ int h[NBKT];
  __shared__ int lb[NBKT];
  __shared__ int gb[NBKT];
  __shared__ int2 pay[TILEA];   // 64 KB
  const int t = threadIdx.x;
  const int base = blockIdx.x * TILEA;

  h[t] = 0;
  __syncthreads();

  int rnk[16], bb[16], loc[16];
#pragma unroll
  for (int k = 0; k < 16; ++k) {
    int i = base + k * 512 + t;
    rnk[k] = -1; bb[k] = 0; loc[k] = 0;
    if (i < nE) {
      int row = erow[i];
      bb[k] = row >> 8;
      loc[k] = row & 255;
      rnk[k] = atomicAdd(&h[bb[k]], 1);
    }
  }
  __syncthreads();

  int hv = h[t];
  lb[t] = hv;
  __syncthreads();
  for (int d = 1; d < NBKT; d <<= 1) {
    int tmp = (t >= d) ? lb[t - d] : 0;
    __syncthreads();
    lb[t] += tmp;
    __syncthreads();
  }
  int ex = lb[t] - hv;
  __syncthreads();
  lb[t] = ex;
  if (hv > 0) gb[t] = atomicAdd(&bcursor[t * 16], hv);
  __syncthreads();

#pragma unroll
  for (int k = 0; k < 16; ++k) {
    int i = base + k * 512 + t;
    if (i < nE) {
      int pos = lb[bb[k]] + rnk[k];
      pay[pos] = make_int2(ecol[i] | (loc[k] << 20), __float_as_int(ew[i]));
    }
  }
  __syncthreads();

  const int wv = t >> 6, lane = t & 63;
  for (int b = wv; b < NBKT; b += 8) {
    int len = h[b];
    if (!len) continue;
    int lbase = lb[b], gbase = gb[b];
    for (int off = lane; off < len; off += 64)
      tmpCW[gbase + off] = pay[lbase + off];
  }
}

// ---------------------------------------------------------------------------
// Pass B: one block per bucket; per-node hist+scan -> offsets; scatter into
// the bucket's 64KB window (single-writer, L2-resident).
// ---------------------------------------------------------------------------
__global__ __launch_bounds__(256) void bin_fine(const int2* __restrict__ tmpCW,
                                                const int* __restrict__ bbase,
                                                const int* __restrict__ bcnt,
                                                int* __restrict__ offsets,
                                                int2* __restrict__ cw,
                                                int nNodes, int nE) {
  __shared__ int hist[256];
  __shared__ int cur[256];
  const int b = blockIdx.x;
  const int t = threadIdx.x;
  const int base = bbase[b];
  const int n = bcnt[b];

  hist[t] = 0;
  __syncthreads();
  for (int i = t; i < n; i += 256)
    atomicAdd(&hist[((uint)tmpCW[base + i].x) >> 20], 1);
  __syncthreads();

  int hv = hist[t];
  cur[t] = hv;
  __syncthreads();
  for (int d = 1; d < 256; d <<= 1) {
    int tmp = (t >= d) ? cur[t - d] : 0;
    __syncthreads();
    cur[t] += tmp;
    __syncthreads();
  }
  int ex = cur[t] - hv;
  __syncthreads();
  cur[t] = ex;
  int node = (b << 8) + t;
  if (node < nNodes) offsets[node] = base + ex;
  if (b == 0 && t == 0) offsets[nNodes] = nE;
  __syncthreads();

  for (int i = t; i < n; i += 256) {
    int2 v = tmpCW[base + i];
    int local = ((uint)v.x) >> 20;
    int d = base + atomicAdd(&cur[local], 1);
    cw[d] = make_int2(v.x & 0xFFFFF, v.y);
  }
}

// ---------------------------------------------------------------------------
// Gather half-pass (feats [128h, 128h+128)): one wave per node; live XF slice
// is 25.6 MB (working-set experiment). Bitonic column sort kept (mild +).
// Lane l covers feats half*128 + 2l, 2l+1 (ushort2 loads, f32x2 nt store).
// ---------------------------------------------------------------------------
__global__ __launch_bounds__(256) void gather_half(const ushort* __restrict__ XFh,
                                                   const int* __restrict__ offsets,
                                                   const int2* __restrict__ cw,
                                                   f32x2* __restrict__ outv,
                                                   int nNodes, int half) {
  const int lane = threadIdx.x & 63;
  const int node = (blockIdx.x * blockDim.x + threadIdx.x) >> 6;
  if (node >= nNodes) return;
  const int start = offsets[node];
  const int end = offsets[node + 1];
  const ushort2* XV = (const ushort2*)XFh;  // 128 ushort2 per row
  const int fo = half * 64 + lane;          // ushort2 index within row

  float ax = 0.f, ay = 0.f;
  for (int base = start; base < end; base += 64) {
    int n = end - base;
    if (n > 64) n = 64;
    int2 e = make_int2(0, 0);
    if (lane < n) {
      long long raw = __builtin_nontemporal_load((const long long*)(cw + base + lane));
      e.x = (int)(raw & 0xFFFFFFFFll);
      e.y = (int)(raw >> 32);
    }
    // bitonic sort by column; key=(col<<6)|lane unique; pad lanes sort last
    int skey = (lane < n) ? ((e.x << 6) | lane) : ((0xFFFFF << 6) | lane);
    int sval = e.y;
#pragma unroll
    for (int k = 2; k <= 64; k <<= 1) {
#pragma unroll
      for (int j = k >> 1; j > 0; j >>= 1) {
        int pk = __shfl_xor(skey, j);
        int pv = __shfl_xor(sval, j);
        bool take_min = ((lane & k) == 0) == ((lane & j) == 0);
        bool keep = (take_min == (skey < pk));
        skey = keep ? skey : pk;
        sval = keep ? sval : pv;
      }
    }
    e.x = ((uint)skey) >> 6;
    e.y = sval;

    int j = 0;
    for (; j + 7 < n; j += 8) {
      int c0 = __shfl(e.x, j),     c1 = __shfl(e.x, j + 1);
      int c2 = __shfl(e.x, j + 2), c3 = __shfl(e.x, j + 3);
      int c4 = __shfl(e.x, j + 4), c5 = __shfl(e.x, j + 5);
      int c6 = __shfl(e.x, j + 6), c7 = __shfl(e.x, j + 7);
      float w0 = __int_as_float(__shfl(e.y, j));
      float w1 = __int_as_float(__shfl(e.y, j + 1));
      float w2 = __int_as_float(__shfl(e.y, j + 2));
      float w3 = __int_as_float(__shfl(e.y, j + 3));
      float w4 = __int_as_float(__shfl(e.y, j + 4));
      float w5 = __int_as_float(__shfl(e.y, j + 5));
      float w6 = __int_as_float(__shfl(e.y, j + 6));
      float w7 = __int_as_float(__shfl(e.y, j + 7));
      ushort2 v0 = XV[(size_t)c0 * 128 + fo];
      ushort2 v1 = XV[(size_t)c1 * 128 + fo];
      ushort2 v2 = XV[(size_t)c2 * 128 + fo];
      ushort2 v3 = XV[(size_t)c3 * 128 + fo];
      ushort2 v4 = XV[(size_t)c4 * 128 + fo];
      ushort2 v5 = XV[(size_t)c5 * 128 + fo];
      ushort2 v6 = XV[(size_t)c6 * 128 + fo];
      ushort2 v7 = XV[(size_t)c7 * 128 + fo];
      ax += w0 * bf2f(v0.x); ay += w0 * bf2f(v0.y);
      ax += w1 * bf2f(v1.x); ay += w1 * bf2f(v1.y);
      ax += w2 * bf2f(v2.x); ay += w2 * bf2f(v2.y);
      ax += w3 * bf2f(v3.x); ay += w3 * bf2f(v3.y);
      ax += w4 * bf2f(v4.x); ay += w4 * bf2f(v4.y);
      ax += w5 * bf2f(v5.x); ay += w5 * bf2f(v5.y);
      ax += w6 * bf2f(v6.x); ay += w6 * bf2f(v6.y);
      ax += w7 * bf2f(v7.x); ay += w7 * bf2f(v7.y);
    }
    for (; j + 3 < n; j += 4) {
      int c0 = __shfl(e.x, j),     c1 = __shfl(e.x, j + 1);
      int c2 = __shfl(e.x, j + 2), c3 = __shfl(e.x, j + 3);
      float w0 = __int_as_float(__shfl(e.y, j));
      float w1 = __int_as_float(__shfl(e.y, j + 1));
      float w2 = __int_as_float(__shfl(e.y, j + 2));
      float w3 = __int_as_float(__shfl(e.y, j + 3));
      ushort2 v0 = XV[(size_t)c0 * 128 + fo];
      ushort2 v1 = XV[(size_t)c1 * 128 + fo];
      ushort2 v2 = XV[(size_t)c2 * 128 + fo];
      ushort2 v3 = XV[(size_t)c3 * 128 + fo];
      ax += w0 * bf2f(v0.x); ay += w0 * bf2f(v0.y);
      ax += w1 * bf2f(v1.x); ay += w1 * bf2f(v1.y);
      ax += w2 * bf2f(v2.x); ay += w2 * bf2f(v2.y);
      ax += w3 * bf2f(v3.x); ay += w3 * bf2f(v3.y);
    }
    for (; j < n; ++j) {
      int c0 = __shfl(e.x, j);
      float w0 = __int_as_float(__shfl(e.y, j));
      ushort2 v0 = XV[(size_t)c0 * 128 + fo];
      ax += w0 * bf2f(v0.x); ay += w0 * bf2f(v0.y);
    }
  }
  f32x2 r; r.x = ax; r.y = ay;
  __builtin_nontemporal_store(r, &outv[(size_t)node * 128 + fo]);
}

// ---------------------------------------------------------------------------
// Fallback path (ws too small / shapes off): f32 GEMM + atomic scatter
// ---------------------------------------------------------------------------
__global__ __launch_bounds__(256) void gemm_xf(const float* __restrict__ x,
                                               const float* __restrict__ F,
                                               float* __restrict__ XF, int M) {
  __shared__ float xs[64][NF];
  const int t = threadIdx.x;
  const int row0 = blockIdx.x * 64;
  const int rows = min(64, M - row0);
  const float4* xv = (const float4*)(x + (size_t)row0 * NF);
  float4* xsv = (float4*)&xs[0][0];
#pragma unroll
  for (int j = 0; j < 16; ++j) {
    int i = j * 256 + t;
    int r = i >> 6;
    float4 v;
    if (r < rows) v = xv[i];
    else          v = make_float4(0.f, 0.f, 0.f, 0.f);
    xsv[i] = v;
  }
  __syncthreads();
  const int r0 = (t >> 5) * 8;
  const int c0 = blockIdx.y * 128 + (t & 31) * 4;
  float acc[8][4];
#pragma unroll
  for (int r = 0; r < 8; ++r)
#pragma unroll
    for (int c = 0; c < 4; ++c) acc[r][c] = 0.f;
  for (int k = 0; k < NF; k += 4) {
    float4 f0 = *(const float4*)(F + (size_t)(k + 0) * NK + c0);
    float4 f1 = *(const float4*)(F + (size_t)(k + 1) * NK + c0);
    float4 f2 = *(const float4*)(F + (size_t)(k + 2) * NK + c0);
    float4 f3 = *(const float4*)(F + (size_t)(k + 3) * NK + c0);
#pragma unroll
    for (int r = 0; r < 8; ++r) {
      float4 xr = *(const float4*)&xs[r0 + r][k];
      acc[r][0] += xr.x * f0.x + xr.y * f1.x + xr.z * f2.x + xr.w * f3.x;
      acc[r][1] += xr.x * f0.y + xr.y * f1.y + xr.z * f2.y + xr.w * f3.y;
      acc[r][2] += xr.x * f0.z + xr.y * f1.z + xr.z * f2.z + xr.w * f3.z;
      acc[r][3] += xr.x * f0.w + xr.y * f1.w + xr.z * f2.w + xr.w * f3.w;
    }
  }
#pragma unroll
  for (int r = 0; r < 8; ++r) {
    int row = r0 + r;
    if (row < rows) {
      float4 v = make_float4(acc[r][0], acc[r][1], acc[r][2], acc[r][3]);
      *(float4*)(XF + (size_t)(row0 + row) * NK + c0) = v;
    }
  }
}

__global__ __launch_bounds__(256) void scatter_edges(
    const float* __restrict__ XF, const int* __restrict__ erow,
    const int* __restrict__ ecol, const float* __restrict__ ew,
    float* __restrict__ out, int nE) {
  const int lane = threadIdx.x & 63;
  const int wid = (blockIdx.x * blockDim.x + threadIdx.x) >> 6;
  const int nwaves = (gridDim.x * blockDim.x) >> 6;
  for (int e = wid; e < nE; e += nwaves) {
    const int r = erow[e];
    const int c = ecol[e];
    const float w = ew[e];
    float4 v = *(const float4*)(XF + (size_t)c * NK + lane * 4);
    float* dst = out + (size_t)r * NK + lane * 4;
    atomicAdd(dst + 0, w * v.x);
    atomicAdd(dst + 1, w * v.y);
    atomicAdd(dst + 2, w * v.z);
    atomicAdd(dst + 3, w * v.w);
  }
}

static inline size_t align16(size_t x) { return (x + 15) & ~(size_t)15; }

extern "C" void kernel_launch(void* const* d_in, const int* in_sizes, int n_in,
                              void* d_out, int out_size, void* d_ws, size_t ws_size,
                              hipStream_t stream) {
  const float* x  = (const float*)d_in[0];
  const float* F  = (const float*)d_in[1];
  const int* erow = (const int*)d_in[2];
  const int* ecol = (const int*)d_in[3];
  const float* ew = (const float*)d_in[4];
  float* out      = (float*)d_out;

  const int M      = in_sizes[0] / NF;
  const int nE     = in_sizes[2];
  const int nNodes = out_size / NK;

  // ---- workspace layout ----
  char* base = (char*)d_ws;
  size_t off = 0;
  ushort* XFh  = (ushort*)(base + off); off += align16((size_t)M * NK * sizeof(ushort));
  ushort* Ft   = (ushort*)(base + off); off += align16((size_t)NF * NK * sizeof(ushort));
  int* offsets = (int*)(base + off);    off += align16(((size_t)nNodes + 1) * sizeof(int));
  int* bcnt    = (int*)(base + off);    off += align16(NBKT * sizeof(int));
  int* bbase   = (int*)(base + off);    off += align16(NBKT * sizeof(int));
  int* bcursor = (int*)(base + off);    off += align16((size_t)NBKT * 16 * sizeof(int));
  int2* tmpCW  = (int2*)(base + off);   off += align16((size_t)nE * sizeof(int2));
  int2* cw     = (int2*)(base + off);   off += align16((size_t)nE * sizeof(int2));
  const size_t needed = off;

  const int nb2 = (nNodes + 255) >> 8;        // fine buckets
  const bool ok = (ws_size >= needed) && (nb2 <= NBKT) &&
                  (nNodes < (1 << 20)) && (M < (1 << 20));

  if (ok) {
    hipMemsetAsync(bcnt, 0, NBKT * sizeof(int), stream);
    // ---- fused filter-transpose + coarse histogram ----
    prelude<<<NF + 2048, 256, 0, stream>>>(F, Ft, erow, bcnt, nE);
    // ---- GEMM (bf16 MFMA, 32-row blocks) ----
    gemm_mfma<<<(M + 31) / 32, 256, 0, stream>>>(x, Ft, XFh, M);
    // ---- CSR build ----
    scan_bbase<<<1, NBKT, 0, stream>>>(bcnt, bbase, bcursor);
    bin_coarse<<<(nE + TILEA - 1) / TILEA, 512, 0, stream>>>(erow, ecol, ew,
                                                             bcursor, tmpCW, nE);
    bin_fine<<<nb2, 256, 0, stream>>>(tmpCW, bbase, bcnt, offsets, cw, nNodes, nE);
    // ---- gather: two sequential feature-half passes (working-set 25.6 MB) ----
    int gblocks = (nNodes + 3) / 4;
    gather_half<<<gblocks, 256, 0, stream>>>(XFh, offsets, cw, (f32x2*)out, nNodes, 0);
    gather_half<<<gblocks, 256, 0, stream>>>(XFh, offsets, cw, (f32x2*)out, nNodes, 1);
  } else {
    // ---- fallback: f32 GEMM + atomic scatter ----
    float* XF = (float*)d_ws;
    dim3 gg((M + 63) / 64, NK / 128);
    gemm_xf<<<gg, 256, 0, stream>>>(x, F, XF, M);
    hipMemsetAsync(d_out, 0, (size_t)out_size * sizeof(float), stream);
    scatter_edges<<<2048, 256, 0, stream>>>(XF, erow, ecol, ew, out, nE);
  }
}

// Round 12
// 417.525 us; speedup vs baseline: 1.0408x; 1.0408x over previous
//
#include <hip/hip_runtime.h>

#define NF 256   // input features
#define NK 256   // filters / output features
#define NBKT 512          // coarse buckets (256 nodes each)
#define TILEA 8192        // edges per bin_coarse block

typedef __attribute__((ext_vector_type(8))) short bf16x8;
typedef __attribute__((ext_vector_type(4))) float f32x4;

__device__ __forceinline__ ushort f2bf(float f) {
  uint u = __float_as_uint(f);
  return (ushort)((u + 0x7fffu + ((u >> 16) & 1u)) >> 16);  // RNE
}
__device__ __forceinline__ float bf2f(ushort h) {
  return __uint_as_float(((uint)h) << 16);
}

// ---------------------------------------------------------------------------
// Prelude (fused): blocks [0,256) transpose filters f32->bf16 Ft[N][K];
// blocks [256, 256+2048) do the coarse bucket histogram (row>>8).
// ---------------------------------------------------------------------------
__global__ __launch_bounds__(256) void prelude(const float* __restrict__ F,
                                               ushort* __restrict__ Ft,
                                               const int* __restrict__ erow,
                                               int* __restrict__ bcnt, int nE) {
  __shared__ int h[NBKT];
  if (blockIdx.x < NF) {
    int k = blockIdx.x;
    int n = threadIdx.x;
    Ft[(size_t)n * NF + k] = f2bf(F[(size_t)k * NK + n]);
    return;
  }
  const int bid = blockIdx.x - NF;
  const int nb = gridDim.x - NF;
  h[threadIdx.x] = 0;
  h[threadIdx.x + 256] = 0;
  __syncthreads();
  for (int e = bid * 256 + threadIdx.x; e < nE; e += nb * 256)
    atomicAdd(&h[erow[e] >> 8], 1);
  __syncthreads();
  int v0 = h[threadIdx.x], v1 = h[threadIdx.x + 256];
  if (v0) atomicAdd(&bcnt[threadIdx.x], v0);
  if (v1) atomicAdd(&bcnt[threadIdx.x + 256], v1);
}

// ---------------------------------------------------------------------------
// MFMA GEMM: 64 rows/block, rt-outer (A-frags from LDS, B-frags L1-hot).
// Live regs per rt: afr[8] + acc[4] — low pressure. Frag math verified r3/r8.
// ---------------------------------------------------------------------------
__global__ __launch_bounds__(256) void gemm_mfma(const float* __restrict__ x,
                                                 const ushort* __restrict__ Ft,
                                                 ushort* __restrict__ XFh, int M) {
  __shared__ ushort As[64 * NF];  // 32 KB, swizzled
  const int t = threadIdx.x;
  const int row0 = blockIdx.x * 64;

  const float4* xv = (const float4*)(x + (size_t)row0 * NF);
#pragma unroll
  for (int j = 0; j < 16; ++j) {
    int idx = j * 256 + t;   // 0..4095
    int r = idx >> 6;        // 0..63
    int c4 = idx & 63;
    float4 v = make_float4(0.f, 0.f, 0.f, 0.f);
    if (row0 + r < M) v = xv[idx];
    ushort4 hh = make_ushort4(f2bf(v.x), f2bf(v.y), f2bf(v.z), f2bf(v.w));
    uint boff = (uint)(r * 512 + c4 * 8);
    boff ^= (uint)((r & 7) << 4);
    *(ushort4*)((char*)As + boff) = hh;
  }
  __syncthreads();

  const int lane = t & 63;
  const int wv = t >> 6;
  const int arow = lane & 15;
  const int kg = lane >> 4;
  const int ncol0 = wv * 64;

#pragma unroll
  for (int rt = 0; rt < 4; ++rt) {
    bf16x8 afr[8];
#pragma unroll
    for (int kk = 0; kk < 8; ++kk) {
      int r = rt * 16 + arow;
      uint boff = (uint)(r * 512 + kk * 64 + kg * 16);
      boff ^= (uint)((r & 7) << 4);
      afr[kk] = *(const bf16x8*)((const char*)As + boff);
    }

    f32x4 acc[4];
#pragma unroll
    for (int f = 0; f < 4; ++f) acc[f] = (f32x4){0.f, 0.f, 0.f, 0.f};

#pragma unroll
    for (int f = 0; f < 4; ++f) {
      const ushort* bp = Ft + (size_t)(ncol0 + f * 16 + arow) * NF + kg * 8;
#pragma unroll
      for (int kk = 0; kk < 8; ++kk) {
        bf16x8 bfr = *(const bf16x8*)(bp + kk * 32);
        acc[f] = __builtin_amdgcn_mfma_f32_16x16x32_bf16(afr[kk], bfr, acc[f], 0, 0, 0);
      }
    }

#pragma unroll
    for (int f = 0; f < 4; ++f) {
      int col = ncol0 + f * 16 + arow;
#pragma unroll
      for (int rg = 0; rg < 4; ++rg) {
        int row = row0 + rt * 16 + kg * 4 + rg;
        if (row < M) XFh[(size_t)row * NK + col] = f2bf(acc[f][rg]);
      }
    }
  }
}

// 1 block, 512 threads: exclusive scan of bcnt -> bbase + bcursor (padded)
__global__ __launch_bounds__(512) void scan_bbase(const int* __restrict__ bcnt,
                                                  int* __restrict__ bbase,
                                                  int* __restrict__ bcursor) {
  __shared__ int s[NBKT];
  int t = threadIdx.x;
  int v = bcnt[t];
  s[t] = v;
  __syncthreads();
  for (int d = 1; d < NBKT; d <<= 1) {
    int tmp = (t >= d) ? s[t - d] : 0;
    __syncthreads();
    s[t] += tmp;
    __syncthreads();
  }
  int excl = s[t] - v;
  bbase[t] = excl;
  bcursor[t * 16] = excl;
}

// ---------------------------------------------------------------------------
// Pass A: coarse bin with LDS permute -> wave-contiguous global runs.
// Payload packs (col | local<<20, w).
// ---------------------------------------------------------------------------
__global__ __launch_bounds__(512) void bin_coarse(const int* __restrict__ erow,
                                                  const int* __restrict__ ecol,
                                                  const float* __restrict__ ew,
                                                  int* __restrict__ bcursor,
                                                  int2* __restrict__ tmpCW, int nE) {
  __shared__ int h[NBKT];
  __shared__ int lb[NBKT];
  __shared__ int gb[NBKT];
  __shared__ int2 pay[TILEA];   // 64 KB
  const int t = threadIdx.x;
  const int base = blockIdx.x * TILEA;

  h[t] = 0;
  __syncthreads();

  int rnk[16], bb[16], loc[16];
#pragma unroll
  for (int k = 0; k < 16; ++k) {
    int i = base + k * 512 + t;
    rnk[k] = -1; bb[k] = 0; loc[k] = 0;
    if (i < nE) {
      int row = erow[i];
      bb[k] = row >> 8;
      loc[k] = row & 255;
      rnk[k] = atomicAdd(&h[bb[k]], 1);
    }
  }
  __syncthreads();

  int hv = h[t];
  lb[t] = hv;
  __syncthreads();
  for (int d = 1; d < NBKT; d <<= 1) {
    int tmp = (t >= d) ? lb[t - d] : 0;
    __syncthreads();
    lb[t] += tmp;
    __syncthreads();
  }
  int ex = lb[t] - hv;
  __syncthreads();
  lb[t] = ex;
  if (hv > 0) gb[t] = atomicAdd(&bcursor[t * 16], hv);
  __syncthreads();

#pragma unroll
  for (int k = 0; k < 16; ++k) {
    int i = base + k * 512 + t;
    if (i < nE) {
      int pos = lb[bb[k]] + rnk[k];
      pay[pos] = make_int2(ecol[i] | (loc[k] << 20), __float_as_int(ew[i]));
    }
  }
  __syncthreads();

  const int wv = t >> 6, lane = t & 63;
  for (int b = wv; b < NBKT; b += 8) {
    int len = h[b];
    if (!len) continue;
    int lbase = lb[b], gbase = gb[b];
    for (int off = lane; off < len; off += 64)
      tmpCW[gbase + off] = pay[lbase + off];
  }
}

// ---------------------------------------------------------------------------
// Pass B: one block per bucket; per-node hist+scan -> offsets; scatter into
// the bucket's 64KB window (single-writer, L2-resident).
// ---------------------------------------------------------------------------
__global__ __launch_bounds__(256) void bin_fine(const int2* __restrict__ tmpCW,
                                                const int* __restrict__ bbase,
                                                const int* __restrict__ bcnt,
                                                int* __restrict__ offsets,
                                                int2* __restrict__ cw,
                                                int nNodes, int nE) {
  __shared__ int hist[256];
  __shared__ int cur[256];
  const int b = blockIdx.x;
  const int t = threadIdx.x;
  const int base = bbase[b];
  const int n = bcnt[b];

  hist[t] = 0;
  __syncthreads();
  for (int i = t; i < n; i += 256)
    atomicAdd(&hist[((uint)tmpCW[base + i].x) >> 20], 1);
  __syncthreads();

  int hv = hist[t];
  cur[t] = hv;
  __syncthreads();
  for (int d = 1; d < 256; d <<= 1) {
    int tmp = (t >= d) ? cur[t - d] : 0;
    __syncthreads();
    cur[t] += tmp;
    __syncthreads();
  }
  int ex = cur[t] - hv;
  __syncthreads();
  cur[t] = ex;
  int node = (b << 8) + t;
  if (node < nNodes) offsets[node] = base + ex;
  if (b == 0 && t == 0) offsets[nNodes] = nE;
  __syncthreads();

  for (int i = t; i < n; i += 256) {
    int2 v = tmpCW[base + i];
    int local = ((uint)v.x) >> 20;
    int d = base + atomicAdd(&cur[local], 1);
    cw[d] = make_int2(v.x & 0xFFFFF, v.y);
  }
}

// ---------------------------------------------------------------------------
// Gather (bf16 XF): one wave per node; bitonic column sort per batch (mild +);
// 8-deep MLP; nt cw loads; nt out stores.
// ---------------------------------------------------------------------------
__global__ __launch_bounds__(256) void gather_bf16(const ushort* __restrict__ XFh,
                                                   const int* __restrict__ offsets,
                                                   const int2* __restrict__ cw,
                                                   f32x4* __restrict__ outv,
                                                   int nNodes) {
  const int lane = threadIdx.x & 63;
  const int node = (blockIdx.x * blockDim.x + threadIdx.x) >> 6;
  if (node >= nNodes) return;
  const int start = offsets[node];
  const int end = offsets[node + 1];
  const ushort4* XV = (const ushort4*)XFh;

  float ax = 0.f, ay = 0.f, az = 0.f, aw = 0.f;
  for (int base = start; base < end; base += 64) {
    int n = end - base;
    if (n > 64) n = 64;
    int2 e = make_int2(0, 0);
    if (lane < n) {
      long long raw = __builtin_nontemporal_load((const long long*)(cw + base + lane));
      e.x = (int)(raw & 0xFFFFFFFFll);
      e.y = (int)(raw >> 32);
    }
    int skey = (lane < n) ? ((e.x << 6) | lane) : ((0xFFFFF << 6) | lane);
    int sval = e.y;
#pragma unroll
    for (int k = 2; k <= 64; k <<= 1) {
#pragma unroll
      for (int j = k >> 1; j > 0; j >>= 1) {
        int pk = __shfl_xor(skey, j);
        int pv = __shfl_xor(sval, j);
        bool take_min = ((lane & k) == 0) == ((lane & j) == 0);
        bool keep = (take_min == (skey < pk));
        skey = keep ? skey : pk;
        sval = keep ? sval : pv;
      }
    }
    e.x = ((uint)skey) >> 6;
    e.y = sval;

    int j = 0;
    for (; j + 7 < n; j += 8) {
      int c0 = __shfl(e.x, j),     c1 = __shfl(e.x, j + 1);
      int c2 = __shfl(e.x, j + 2), c3 = __shfl(e.x, j + 3);
      int c4 = __shfl(e.x, j + 4), c5 = __shfl(e.x, j + 5);
      int c6 = __shfl(e.x, j + 6), c7 = __shfl(e.x, j + 7);
      float w0 = __int_as_float(__shfl(e.y, j));
      float w1 = __int_as_float(__shfl(e.y, j + 1));
      float w2 = __int_as_float(__shfl(e.y, j + 2));
      float w3 = __int_as_float(__shfl(e.y, j + 3));
      float w4 = __int_as_float(__shfl(e.y, j + 4));
      float w5 = __int_as_float(__shfl(e.y, j + 5));
      float w6 = __int_as_float(__shfl(e.y, j + 6));
      float w7 = __int_as_float(__shfl(e.y, j + 7));
      ushort4 v0 = XV[(size_t)c0 * 64 + lane];
      ushort4 v1 = XV[(size_t)c1 * 64 + lane];
      ushort4 v2 = XV[(size_t)c2 * 64 + lane];
      ushort4 v3 = XV[(size_t)c3 * 64 + lane];
      ushort4 v4 = XV[(size_t)c4 * 64 + lane];
      ushort4 v5 = XV[(size_t)c5 * 64 + lane];
      ushort4 v6 = XV[(size_t)c6 * 64 + lane];
      ushort4 v7 = XV[(size_t)c7 * 64 + lane];
      ax += w0 * bf2f(v0.x); ay += w0 * bf2f(v0.y); az += w0 * bf2f(v0.z); aw += w0 * bf2f(v0.w);
      ax += w1 * bf2f(v1.x); ay += w1 * bf2f(v1.y); az += w1 * bf2f(v1.z); aw += w1 * bf2f(v1.w);
      ax += w2 * bf2f(v2.x); ay += w2 * bf2f(v2.y); az += w2 * bf2f(v2.z); aw += w2 * bf2f(v2.w);
      ax += w3 * bf2f(v3.x); ay += w3 * bf2f(v3.y); az += w3 * bf2f(v3.z); aw += w3 * bf2f(v3.w);
      ax += w4 * bf2f(v4.x); ay += w4 * bf2f(v4.y); az += w4 * bf2f(v4.z); aw += w4 * bf2f(v4.w);
      ax += w5 * bf2f(v5.x); ay += w5 * bf2f(v5.y); az += w5 * bf2f(v5.z); aw += w5 * bf2f(v5.w);
      ax += w6 * bf2f(v6.x); ay += w6 * bf2f(v6.y); az += w6 * bf2f(v6.z); aw += w6 * bf2f(v6.w);
      ax += w7 * bf2f(v7.x); ay += w7 * bf2f(v7.y); az += w7 * bf2f(v7.z); aw += w7 * bf2f(v7.w);
    }
    for (; j + 3 < n; j += 4) {
      int c0 = __shfl(e.x, j),     c1 = __shfl(e.x, j + 1);
      int c2 = __shfl(e.x, j + 2), c3 = __shfl(e.x, j + 3);
      float w0 = __int_as_float(__shfl(e.y, j));
      float w1 = __int_as_float(__shfl(e.y, j + 1));
      float w2 = __int_as_float(__shfl(e.y, j + 2));
      float w3 = __int_as_float(__shfl(e.y, j + 3));
      ushort4 v0 = XV[(size_t)c0 * 64 + lane];
      ushort4 v1 = XV[(size_t)c1 * 64 + lane];
      ushort4 v2 = XV[(size_t)c2 * 64 + lane];
      ushort4 v3 = XV[(size_t)c3 * 64 + lane];
      ax += w0 * bf2f(v0.x); ay += w0 * bf2f(v0.y); az += w0 * bf2f(v0.z); aw += w0 * bf2f(v0.w);
      ax += w1 * bf2f(v1.x); ay += w1 * bf2f(v1.y); az += w1 * bf2f(v1.z); aw += w1 * bf2f(v1.w);
      ax += w2 * bf2f(v2.x); ay += w2 * bf2f(v2.y); az += w2 * bf2f(v2.z); aw += w2 * bf2f(v2.w);
      ax += w3 * bf2f(v3.x); ay += w3 * bf2f(v3.y); az += w3 * bf2f(v3.z); aw += w3 * bf2f(v3.w);
    }
    for (; j < n; ++j) {
      int c0 = __shfl(e.x, j);
      float w0 = __int_as_float(__shfl(e.y, j));
      ushort4 v0 = XV[(size_t)c0 * 64 + lane];
      ax += w0 * bf2f(v0.x); ay += w0 * bf2f(v0.y); az += w0 * bf2f(v0.z); aw += w0 * bf2f(v0.w);
    }
  }
  f32x4 r; r.x = ax; r.y = ay; r.z = az; r.w = aw;
  __builtin_nontemporal_store(r, &outv[(size_t)node * 64 + lane]);
}

// ---------------------------------------------------------------------------
// Fallback path (ws too small / shapes off): f32 GEMM + atomic scatter
// ---------------------------------------------------------------------------
__global__ __launch_bounds__(256) void gemm_xf(const float* __restrict__ x,
                                               const float* __restrict__ F,
                                               float* __restrict__ XF, int M) {
  __shared__ float xs[64][NF];
  const int t = threadIdx.x;
  const int row0 = blockIdx.x * 64;
  const int rows = min(64, M - row0);
  const float4* xv = (const float4*)(x + (size_t)row0 * NF);
  float4* xsv = (float4*)&xs[0][0];
#pragma unroll
  for (int j = 0; j < 16; ++j) {
    int i = j * 256 + t;
    int r = i >> 6;
    float4 v;
    if (r < rows) v = xv[i];
    else          v = make_float4(0.f, 0.f, 0.f, 0.f);
    xsv[i] = v;
  }
  __syncthreads();
  const int r0 = (t >> 5) * 8;
  const int c0 = blockIdx.y * 128 + (t & 31) * 4;
  float acc[8][4];
#pragma unroll
  for (int r = 0; r < 8; ++r)
#pragma unroll
    for (int c = 0; c < 4; ++c) acc[r][c] = 0.f;
  for (int k = 0; k < NF; k += 4) {
    float4 f0 = *(const float4*)(F + (size_t)(k + 0) * NK + c0);
    float4 f1 = *(const float4*)(F + (size_t)(k + 1) * NK + c0);
    float4 f2 = *(const float4*)(F + (size_t)(k + 2) * NK + c0);
    float4 f3 = *(const float4*)(F + (size_t)(k + 3) * NK + c0);
#pragma unroll
    for (int r = 0; r < 8; ++r) {
      float4 xr = *(const float4*)&xs[r0 + r][k];
      acc[r][0] += xr.x * f0.x + xr.y * f1.x + xr.z * f2.x + xr.w * f3.x;
      acc[r][1] += xr.x * f0.y + xr.y * f1.y + xr.z * f2.y + xr.w * f3.y;
      acc[r][2] += xr.x * f0.z + xr.y * f1.z + xr.z * f2.z + xr.w * f3.z;
      acc[r][3] += xr.x * f0.w + xr.y * f1.w + xr.z * f2.w + xr.w * f3.w;
    }
  }
#pragma unroll
  for (int r = 0; r < 8; ++r) {
    int row = r0 + r;
    if (row < rows) {
      float4 v = make_float4(acc[r][0], acc[r][1], acc[r][2], acc[r][3]);
      *(float4*)(XF + (size_t)(row0 + row) * NK + c0) = v;
    }
  }
}

__global__ __launch_bounds__(256) void scatter_edges(
    const float* __restrict__ XF, const int* __restrict__ erow,
    const int* __restrict__ ecol, const float* __restrict__ ew,
    float* __restrict__ out, int nE) {
  const int lane = threadIdx.x & 63;
  const int wid = (blockIdx.x * blockDim.x + threadIdx.x) >> 6;
  const int nwaves = (gridDim.x * blockDim.x) >> 6;
  for (int e = wid; e < nE; e += nwaves) {
    const int r = erow[e];
    const int c = ecol[e];
    const float w = ew[e];
    float4 v = *(const float4*)(XF + (size_t)c * NK + lane * 4);
    float* dst = out + (size_t)r * NK + lane * 4;
    atomicAdd(dst + 0, w * v.x);
    atomicAdd(dst + 1, w * v.y);
    atomicAdd(dst + 2, w * v.z);
    atomicAdd(dst + 3, w * v.w);
  }
}

static inline size_t align16(size_t x) { return (x + 15) & ~(size_t)15; }

extern "C" void kernel_launch(void* const* d_in, const int* in_sizes, int n_in,
                              void* d_out, int out_size, void* d_ws, size_t ws_size,
                              hipStream_t stream) {
  const float* x  = (const float*)d_in[0];
  const float* F  = (const float*)d_in[1];
  const int* erow = (const int*)d_in[2];
  const int* ecol = (const int*)d_in[3];
  const float* ew = (const float*)d_in[4];
  float* out      = (float*)d_out;

  const int M      = in_sizes[0] / NF;
  const int nE     = in_sizes[2];
  const int nNodes = out_size / NK;

  // ---- workspace layout ----
  char* base = (char*)d_ws;
  size_t off = 0;
  ushort* XFh  = (ushort*)(base + off); off += align16((size_t)M * NK * sizeof(ushort));
  ushort* Ft   = (ushort*)(base + off); off += align16((size_t)NF * NK * sizeof(ushort));
  int* offsets = (int*)(base + off);    off += align16(((size_t)nNodes + 1) * sizeof(int));
  int* bcnt    = (int*)(base + off);    off += align16(NBKT * sizeof(int));
  int* bbase   = (int*)(base + off);    off += align16(NBKT * sizeof(int));
  int* bcursor = (int*)(base + off);    off += align16((size_t)NBKT * 16 * sizeof(int));
  int2* tmpCW  = (int2*)(base + off);   off += align16((size_t)nE * sizeof(int2));
  int2* cw     = (int2*)(base + off);   off += align16((size_t)nE * sizeof(int2));
  const size_t needed = off;

  const int nb2 = (nNodes + 255) >> 8;        // fine buckets
  const bool ok = (ws_size >= needed) && (nb2 <= NBKT) &&
                  (nNodes < (1 << 20)) && (M < (1 << 20));

  if (ok) {
    hipMemsetAsync(bcnt, 0, NBKT * sizeof(int), stream);
    // ---- fused filter-transpose + coarse histogram ----
    prelude<<<NF + 2048, 256, 0, stream>>>(F, Ft, erow, bcnt, nE);
    // ---- GEMM (bf16 MFMA, 64-row blocks, rt-outer) ----
    gemm_mfma<<<(M + 63) / 64, 256, 0, stream>>>(x, Ft, XFh, M);
    // ---- CSR build ----
    scan_bbase<<<1, NBKT, 0, stream>>>(bcnt, bbase, bcursor);
    bin_coarse<<<(nE + TILEA - 1) / TILEA, 512, 0, stream>>>(erow, ecol, ew,
                                                             bcursor, tmpCW, nE);
    bin_fine<<<nb2, 256, 0, stream>>>(tmpCW, bbase, bcnt, offsets, cw, nNodes, nE);
    // ---- gather (column-sorted batches) ----
    int gblocks = (nNodes + 3) / 4;
    gather_bf16<<<gblocks, 256, 0, stream>>>(XFh, offsets, cw, (f32x4*)out, nNodes);
  } else {
    // ---- fallback: f32 GEMM + atomic scatter ----
    float* XF = (float*)d_ws;
    dim3 gg((M + 63) / 64, NK / 128);
    gemm_xf<<<gg, 256, 0, stream>>>(x, F, XF, M);
    hipMemsetAsync(d_out, 0, (size_t)out_size * sizeof(float), stream);
    scatter_edges<<<2048, 256, 0, stream>>>(XF, erow, ecol, ew, out, nE);
  }
}